// Round 3
// baseline (294.585 us; speedup 1.0000x reference)
//
#include <hip/hip_runtime.h>
#include <hip/hip_bf16.h>
#include <math.h>

#define H_ 16
#define KC_ 16
#define ZD_ 64
#define HID_ 256
#define O_ 2048
#define NW2_ 49152                    // OC*IC*KW columns of W2
#define W2D_OUT 37748736              // O*I*KW*L (out dwords, main region)
#define DPDE_ 64
#define WSW_OFF 131072                // byte offset of w in workspace
#define WS_NEED 50462720              // 131072 + 2048*6144*4

typedef short bf16x8 __attribute__((ext_vector_type(8)));
typedef float f32x4 __attribute__((ext_vector_type(4)));

static __device__ __forceinline__ unsigned short f2bf(float f) {
    union { float f; unsigned u; } v; v.f = f;
    unsigned r = v.u + 0x7FFF + ((v.u >> 16) & 1);   // RNE
    return (unsigned short)(r >> 16);
}

static __device__ __forceinline__ unsigned pack2(float lo, float hi) {
    return (unsigned)f2bf(lo) | ((unsigned)f2bf(hi) << 16);
}

// ---------------------------------------------------------------------------
// Prep: per-block redundant mean+feat (pde L2-cached), hidden in MFMA-A layout
// hiddenA[k>>3][m][k&7] bf16, plus bb for blocks 0..7.  grid 256 x 256.
// ---------------------------------------------------------------------------
__global__ void prep_kernel(const float* __restrict__ Z,
                            const float* __restrict__ pde,
                            const float* __restrict__ W1,
                            const float* __restrict__ U1,
                            const float* __restrict__ b1,
                            const float* __restrict__ z_bias,
                            const float* __restrict__ u_bias,
                            unsigned short* __restrict__ hiddenA,
                            float* __restrict__ out_bb) {
    __shared__ float part[16][64];
    __shared__ float meanv[64];
    __shared__ float zr[64];
    const int t = threadIdx.x, m = blockIdx.x;
    if (t < 64) zr[t] = Z[m * ZD_ + t];
    const int c4 = t & 15, rg = t >> 4;
    float sx = 0.f, sy = 0.f, sz = 0.f, sw = 0.f;
    const float4* p = (const float4*)pde;      // 16 float4 per 64-col row
    for (int r = 0; r < 64; ++r) {
        float4 v = p[(rg * 64 + r) * 16 + c4];
        sx += v.x; sy += v.y; sz += v.z; sw += v.w;
    }
    part[rg][c4 * 4 + 0] = sx; part[rg][c4 * 4 + 1] = sy;
    part[rg][c4 * 4 + 2] = sz; part[rg][c4 * 4 + 3] = sw;
    __syncthreads();
    if (t < 64) {
        float a = 0.f;
        #pragma unroll
        for (int g = 0; g < 16; ++g) a += part[g][t];
        meanv[t] = a * (1.f / 1024.f);
    }
    __syncthreads();
    float f = b1[t];
    #pragma unroll
    for (int d = 0; d < 64; ++d) f = fmaf(meanv[d], U1[d * HID_ + t], f);
    float s = f;
    #pragma unroll
    for (int d = 0; d < 64; ++d) s = fmaf(zr[d], W1[d * HID_ + t], s);
    // MFMA-A-native layout: hiddenA[(k/8)*256 + m][k%8]
    hiddenA[((size_t)(t >> 3) * 256 + m) * 8 + (t & 7)] = f2bf(tanhf(s));
    if (m < 8) {
        const int idx = m * 256 + t;
        out_bb[idx] = z_bias[idx] + u_bias[idx];
    }
}

#define BT_S2 132                     // staging row stride in DWORDS

// ---------------------------------------------------------------------------
// Kernel A: MFMA GEMM -> compact w[o][i][kw] f32 (+b2 folded) to workspace.
// grid 512: oc = b>>2, icq = b&3. Stage+MFMA identical to verified R1/R2.
// Epilogue: 48 scalar stores/wave, each instr = 4 x 64B full lines.
// ---------------------------------------------------------------------------
__global__ __launch_bounds__(512, 4)
void gemm_w(const unsigned short* __restrict__ hiddenA,
            const float* __restrict__ W2,
            const float* __restrict__ b2,
            float* __restrict__ wout) {
    __shared__ unsigned bT[96 * BT_S2];

    const int t = threadIdx.x;
    const int lane = t & 63;
    const int wave = t >> 6;
    const int n15 = lane & 15;
    const int quad = lane >> 4;
    const int oc = blockIdx.x >> 2;
    const int icq = blockIdx.x & 3;
    const int n0g = oc * 384 + icq * 96;

    // ---- stage ALL K=256 x 96n of W2, k-pair packed bf16, one pass ----
    #pragma unroll
    for (int i = 0; i < 6; ++i) {
        const int u  = i * 512 + t;
        const int kp = u / 24;
        const int nq = u - kp * 24;
        const float* p0 = W2 + (size_t)(2 * kp) * NW2_ + n0g + nq * 4;
        const float4 va = *(const float4*)p0;
        const float4 vb = *(const float4*)(p0 + NW2_);
        const int kpx = kp ^ ((nq & 7) << 1) ^ (((nq >> 3) & 1) << 4);
        unsigned* r0 = &bT[(4 * nq) * BT_S2 + kpx];
        r0[0 * BT_S2] = pack2(va.x, vb.x);
        r0[1 * BT_S2] = pack2(va.y, vb.y);
        r0[2 * BT_S2] = pack2(va.z, vb.z);
        r0[3 * BT_S2] = pack2(va.w, vb.w);
    }
    __syncthreads();

    f32x4 acc[2][6];
    #pragma unroll
    for (int a = 0; a < 2; ++a)
        #pragma unroll
        for (int b = 0; b < 6; ++b) acc[a][b] = (f32x4){0.f, 0.f, 0.f, 0.f};

    #pragma unroll
    for (int ks = 0; ks < 8; ++ks) {
        const int g = ks * 4 + quad;
        bf16x8 afr[2];
        #pragma unroll
        for (int mi = 0; mi < 2; ++mi)
            afr[mi] = *(const bf16x8*)(hiddenA +
                      ((size_t)g * 256 + (wave * 2 + mi) * 16 + n15) * 8);
        const int base4 = ks * 16 + quad * 4;
        #pragma unroll
        for (int nt = 0; nt < 6; ++nt) {
            const int n = nt * 16 + n15;
            const int nqr = n >> 2;
            const int swz = ((nqr & 7) << 1) ^ (((nqr >> 3) & 1) << 4);
            const unsigned* row = &bT[n * BT_S2];
            union { bf16x8 v; unsigned long long q[2]; } bb;
            bb.q[0] = *(const unsigned long long*)&row[(base4)     ^ swz];
            bb.q[1] = *(const unsigned long long*)&row[(base4 + 2) ^ swz];
            acc[0][nt] = __builtin_amdgcn_mfma_f32_16x16x32_bf16(afr[0], bb.v, acc[0][nt], 0, 0, 0);
            acc[1][nt] = __builtin_amdgcn_mfma_f32_16x16x32_bf16(afr[1], bb.v, acc[1][nt], 0, 0, 0);
        }
    }

    float gb2v[6];
    #pragma unroll
    for (int nt = 0; nt < 6; ++nt) gb2v[nt] = b2[n0g + nt * 16 + n15];

    // w[o][i][kw] linear dword = o*6144 + kc*384 + icq*96 + nl
    #pragma unroll
    for (int mi = 0; mi < 2; ++mi) {
        const int o = (wave * 2 + mi) * 128 + oc;
        float* wb = wout + (size_t)o * 6144 + icq * 96;
        #pragma unroll
        for (int nt = 0; nt < 6; ++nt)
            #pragma unroll
            for (int r = 0; r < 4; ++r)
                wb[(quad * 4 + r) * 384 + nt * 16 + n15] = acc[mi][nt][r] + gb2v[nt];
    }
}

// ---------------------------------------------------------------------------
// Kernel B: pure streaming expansion.  out[e] = w[e/3] * unet[(e/9)*3 + e%3].
// grid 4096 x 256.  Tile = 9216 out dwords; per thread 9 x dwordx4 NT stores.
// No LDS, no barriers; gathers are L1-hot (3x dword reuse within wave).
// ---------------------------------------------------------------------------
__global__ __launch_bounds__(256, 4)
void expand(const float* __restrict__ w,
            const float* __restrict__ unet,
            float* __restrict__ out) {
    const unsigned t = threadIdx.x;
    const unsigned W0 = blockIdx.x * 9216u + t * 4u;
    #pragma unroll
    for (int s = 0; s < 9; ++s) {
        const unsigned W = W0 + (unsigned)s * 1024u;
        const unsigned q   = W / 3u;
        const unsigned rem = W - q * 3u;          // W % 3
        const unsigned i0  = W / 9u;
        const unsigned m9  = W - i0 * 9u;         // W % 9
        const float w0 = w[q];
        const float w1 = w[q + 1u];
        f32x4 r;
        #pragma unroll
        for (int c = 0; c < 4; ++c) {
            const float wv = ((unsigned)c < 3u - rem) ? w0 : w1;
            unsigned lc = rem + (unsigned)c;      // e % 3 (before wrap)
            if (lc >= 3u) lc -= 3u;
            const unsigned ui = (i0 + ((m9 + (unsigned)c) >= 9u ? 1u : 0u)) * 3u + lc;
            r[c] = wv * unet[ui];
        }
        __builtin_nontemporal_store(r, (f32x4*)(out + W));
    }
}

// ---------------------------------------------------------------------------
// Fallback (workspace too small): R2 fused kernel, verified correct.
// ---------------------------------------------------------------------------
#define WL_ST 97
#define WL_SZ 1552

__global__ __launch_bounds__(512, 4)
void gemm_expand(const unsigned short* __restrict__ hiddenA,
                 const float* __restrict__ W2,
                 const float* __restrict__ b2,
                 const float* __restrict__ unet,
                 float* __restrict__ out) {
    __shared__ unsigned bT[96 * BT_S2];

    const int t = threadIdx.x;
    const int lane = t & 63;
    const int wave = t >> 6;
    const int n15 = lane & 15;
    const int quad = lane >> 4;
    const int L = lane & 31;
    const int half = lane >> 5;
    const int oc = blockIdx.x >> 2;
    const int icq = blockIdx.x & 3;
    const int n0g = oc * 384 + icq * 96;

    #pragma unroll
    for (int i = 0; i < 6; ++i) {
        const int u  = i * 512 + t;
        const int kp = u / 24;
        const int nq = u - kp * 24;
        const float* p0 = W2 + (size_t)(2 * kp) * NW2_ + n0g + nq * 4;
        const float4 va = *(const float4*)p0;
        const float4 vb = *(const float4*)(p0 + NW2_);
        const int kpx = kp ^ ((nq & 7) << 1) ^ (((nq >> 3) & 1) << 4);
        unsigned* r0 = &bT[(4 * nq) * BT_S2 + kpx];
        r0[0 * BT_S2] = pack2(va.x, vb.x);
        r0[1 * BT_S2] = pack2(va.y, vb.y);
        r0[2 * BT_S2] = pack2(va.z, vb.z);
        r0[3 * BT_S2] = pack2(va.w, vb.w);
    }
    __syncthreads();

    f32x4 acc[2][6];
    #pragma unroll
    for (int a = 0; a < 2; ++a)
        #pragma unroll
        for (int b = 0; b < 6; ++b) acc[a][b] = (f32x4){0.f, 0.f, 0.f, 0.f};

    #pragma unroll
    for (int ks = 0; ks < 8; ++ks) {
        const int g = ks * 4 + quad;
        bf16x8 afr[2];
        #pragma unroll
        for (int mi = 0; mi < 2; ++mi)
            afr[mi] = *(const bf16x8*)(hiddenA +
                      ((size_t)g * 256 + (wave * 2 + mi) * 16 + n15) * 8);
        const int base4 = ks * 16 + quad * 4;
        #pragma unroll
        for (int nt = 0; nt < 6; ++nt) {
            const int n = nt * 16 + n15;
            const int nqr = n >> 2;
            const int swz = ((nqr & 7) << 1) ^ (((nqr >> 3) & 1) << 4);
            const unsigned* row = &bT[n * BT_S2];
            union { bf16x8 v; unsigned long long q[2]; } bb;
            bb.q[0] = *(const unsigned long long*)&row[(base4)     ^ swz];
            bb.q[1] = *(const unsigned long long*)&row[(base4 + 2) ^ swz];
            acc[0][nt] = __builtin_amdgcn_mfma_f32_16x16x32_bf16(afr[0], bb.v, acc[0][nt], 0, 0, 0);
            acc[1][nt] = __builtin_amdgcn_mfma_f32_16x16x32_bf16(afr[1], bb.v, acc[1][nt], 0, 0, 0);
        }
    }

    float gb2v[6];
    #pragma unroll
    for (int nt = 0; nt < 6; ++nt) gb2v[nt] = b2[n0g + nt * 16 + n15];

    __syncthreads();

    float* wl = ((float*)bT) + wave * WL_SZ;

    #pragma unroll
    for (int mi = 0; mi < 2; ++mi) {
        #pragma unroll
        for (int nt = 0; nt < 6; ++nt)
            #pragma unroll
            for (int r = 0; r < 4; ++r)
                wl[(quad * 4 + r) * WL_ST + nt * 16 + n15] = acc[mi][nt][r] + gb2v[nt];

        const int o = (wave * 2 + mi) * 128 + oc;
        const float* uo = unet + (size_t)o * 6144;
        float* ob = out + (size_t)o * 18432;

        #pragma unroll
        for (int kp = 0; kp < 8; ++kp) {
            const int kc = kp * 2 + half;
            const float* wrow = wl + kc * WL_ST;
            const float* ub = uo + kc * 384 + icq * 96;
            float* os = ob + kc * 1152 + icq * 288;
            #pragma unroll
            for (int j = 0; j < 9; ++j) {
                const int d  = j * 32 + L;
                const int d3 = d / 3;
                const int d9 = d / 9;
                const int l  = d - 3 * d3;
                os[d] = wrow[d3] * ub[d9 * 3 + l];
            }
        }
    }
}

// ---------------------------------------------------------------------------
extern "C" void kernel_launch(void* const* d_in, const int* in_sizes, int n_in,
                              void* d_out, int out_size, void* d_ws, size_t ws_size,
                              hipStream_t stream) {
    const float* Z       = (const float*)d_in[0];
    const float* z_bias  = (const float*)d_in[1];
    const float* unet_w  = (const float*)d_in[2];
    const float* unet_b  = (const float*)d_in[3];
    const float* pde     = (const float*)d_in[4];
    const float* W1      = (const float*)d_in[5];
    const float* U1      = (const float*)d_in[6];
    const float* b1      = (const float*)d_in[7];
    const float* W2      = (const float*)d_in[8];
    const float* b2      = (const float*)d_in[9];
    float* out = (float*)d_out;

    unsigned short* hiddenA = (unsigned short*)d_ws;   // 256*256 bf16 = 128 KB

    prep_kernel<<<256, 256, 0, stream>>>(Z, pde, W1, U1, b1, z_bias, unet_b,
                                         hiddenA, out + W2D_OUT);

    if (ws_size >= (size_t)WS_NEED) {
        float* wbuf = (float*)((char*)d_ws + WSW_OFF);
        gemm_w<<<512, 512, 0, stream>>>(hiddenA, W2, b2, wbuf);
        expand<<<4096, 256, 0, stream>>>(wbuf, unet_w, out);
    } else {
        gemm_expand<<<512, 512, 0, stream>>>(hiddenA, W2, b2, unet_w, out);
    }
}